// Round 11
// baseline (425.927 us; speedup 1.0000x reference)
//
#include <hip/hip_runtime.h>

#define BB 64
#define HH 512
#define WW 512
#define PLANE (HH * WW)
#define N_CHEBY 15

struct Sl { float a, b, c, d; };

__device__ __forceinline__ void racc(const Sl& s, float k0, float k1, float k2,
                                     float& o0, float& o1) {
    o0 = fmaf(k0, s.a, fmaf(k1, s.b, fmaf(k2, s.c, o0)));
    o1 = fmaf(k0, s.b, fmaf(k1, s.c, fmaf(k2, s.d, o1)));
}

__device__ __forceinline__ Sl ldsl(const float* pl, int row, int c2, bool ok) {
    Sl s = {0.f, 0.f, 0.f, 0.f};
    if (ok) {
        const float* rp = pl + (size_t)row * WW;
        float2 v = *reinterpret_cast<const float2*>(rp + c2);
        s.b = v.x; s.c = v.y;
        if (c2 > 0)      s.a = rp[c2 - 1];
        if (c2 + 2 < WW) s.d = rp[c2 + 2];
    }
    return s;
}

// Barrier WITHOUT vmcnt drain: flush LDS ops, leave global loads in flight.
__device__ __forceinline__ void softbar() {
    __asm__ volatile("s_waitcnt lgkmcnt(0)" ::: "memory");
    __builtin_amdgcn_s_barrier();
}

// ---------------------------------------------------------------------------
// Fused FDv-level power pass (row-march, stripe height RR).
// v1 = inv*A(in), v_{j+1} = A(v_j); mz = stripe max|v_{FDv-1}|, mw = max|v_FDv|.
// Config FD=5 @ RR=16, lb(256,4), grid 2048: mirrors the proven cheby config.
// ---------------------------------------------------------------------------
template<int FDv, int RR>
__global__ __launch_bounds__(256, 4) void conv_fusedN(
    const float* __restrict__ in, const float* __restrict__ kern,
    const float* __restrict__ pm_prev, float* __restrict__ out,
    float* __restrict__ pmw, float* __restrict__ pmz)
{
    constexpr int NS = HH / RR;
    const int b = blockIdx.y, stripe = blockIdx.x, ytop = stripe * RR;
    const int t = threadIdx.x, c2 = t << 1;

    __shared__ float re[FDv - 1][2][258], ro[FDv - 1][2][258];
    __shared__ float sred[8];
    __shared__ float sinv;

    if (t < 2 * (FDv - 1)) {
        const int l = t >> 1, par = t & 1;
        re[l][par][0] = 0.f; re[l][par][257] = 0.f;
        ro[l][par][0] = 0.f; ro[l][par][257] = 0.f;
    }
    if (pm_prev && t < 64) {
        float v = (t < NS) ? pm_prev[b * NS + t] : 0.f;
#pragma unroll
        for (int o = 32; o; o >>= 1) v = fmaxf(v, __shfl_xor(v, o, 64));
        if (t == 0) sinv = 1.f / v;
    }
    __syncthreads();
    const float invv = pm_prev ? sinv : 1.f;

    const float* kb = kern + b * 9;
    const float k00=kb[0],k01=kb[1],k02=kb[2],k10=kb[3],k11=kb[4],k12=kb[5],
                k20=kb[6],k21=kb[7],k22=kb[8];
    const float* ip = in + (size_t)b * PLANE;
    float* op = out ? out + (size_t)b * PLANE : nullptr;

    Sl u2 = {0,0,0,0}, u1 = {0,0,0,0};
    Sl ltp[FDv - 1], lmd[FDv - 1];
    float own0[FDv - 1], own1[FDv - 1];
#pragma unroll
    for (int l = 0; l < FDv - 1; ++l) {
        ltp[l] = Sl{0,0,0,0}; lmd[l] = Sl{0,0,0,0};
        own0[l] = 0.f; own1[l] = 0.f;
    }
    float mz = 0.f, mw = 0.f;
    Sl u0 = ldsl(ip, ytop - FDv, c2, (unsigned)(ytop - FDv) < HH);

    const int STEPS   = RR + 3 * FDv - 1;
    const int LOADCUT = RR + 2 * FDv - 1;
#pragma unroll 2
    for (int p = 0; p < STEPS; ++p) {
        const int yu = ytop - FDv + p;
        Sl un = ldsl(ip, yu + 1, c2, ((unsigned)(yu + 1) < HH) && (p < LOADCUT));

        const int rpar = (p + 1) & 1, wpar = p & 1;
        Sl am[FDv - 1];
#pragma unroll
        for (int l = 0; l < FDv - 1; ++l) {
            am[l].a = ro[l][rpar][t];
            am[l].b = own0[l];
            am[l].c = own1[l];
            am[l].d = re[l][rpar][2 + t];
        }

        float v0[FDv], v1[FDv];
        {   // level 1 (normalized)
            float s0 = 0.f, s1 = 0.f;
            racc(u2, k00,k01,k02, s0,s1);
            racc(u1, k10,k11,k12, s0,s1);
            racc(u0, k20,k21,k22, s0,s1);
            const int y = yu - 1;
            const bool act = (y >= ytop - (FDv-1)) && (y <= ytop + RR + FDv - 2)
                          && ((unsigned)y < HH);
            v0[0] = act ? s0 * invv : 0.f;
            v1[0] = act ? s1 * invv : 0.f;
        }
#pragma unroll
        for (int j = 2; j <= FDv; ++j) {
            float s0 = 0.f, s1 = 0.f;
            racc(ltp[j-2], k00,k01,k02, s0,s1);
            racc(lmd[j-2], k10,k11,k12, s0,s1);
            racc(am[j-2],  k20,k21,k22, s0,s1);
            const int y = yu - (2*j - 1);
            if (j < FDv) {
                const bool act = (y >= ytop - (FDv-j)) && (y <= ytop + RR + FDv - j - 1)
                              && ((unsigned)y < HH);
                v0[j-1] = act ? s0 : 0.f;
                v1[j-1] = act ? s1 : 0.f;
                if (j == FDv - 1)
                    mz = fmaxf(mz, fmaxf(fabsf(v0[j-1]), fabsf(v1[j-1])));
            } else {
                if (y >= ytop && y < ytop + RR) {
                    mw = fmaxf(mw, fmaxf(fabsf(s0), fabsf(s1)));
                    if (op)
                        *reinterpret_cast<float2*>(op + (size_t)y * WW + c2) =
                            make_float2(s0, s1);
                }
            }
        }
#pragma unroll
        for (int l = 0; l < FDv - 1; ++l) {
            re[l][wpar][1 + t] = v0[l];
            ro[l][wpar][1 + t] = v1[l];
            ltp[l] = lmd[l]; lmd[l] = am[l];
            own0[l] = v0[l]; own1[l] = v1[l];
        }
        u2 = u1; u1 = u0; u0 = un;
        softbar();
    }

#pragma unroll
    for (int o = 32; o; o >>= 1) {
        mz = fmaxf(mz, __shfl_xor(mz, o, 64));
        mw = fmaxf(mw, __shfl_xor(mw, o, 64));
    }
    if ((t & 63) == 0) { sred[t >> 6] = mz; sred[4 + (t >> 6)] = mw; }
    __syncthreads();
    if (t == 0) {
        pmz[b * NS + stripe] =
            fmaxf(fmaxf(sred[0], sred[1]), fmaxf(sred[2], sred[3]));
        pmw[b * NS + stripe] =
            fmaxf(fmaxf(sred[4], sred[5]), fmaxf(sred[6], sred[7]));
    }
}

// m = max|v20| / max|v19|; taus[it*BB+b].  NS=32 stripes from the conv passes.
__global__ __launch_bounds__(64) void tau_fused(
    const float* __restrict__ pmz, const float* __restrict__ pmw,
    float* __restrict__ taus)
{
    constexpr int NS = 32;
    const int b = blockIdx.x, t = threadIdx.x;
    float vz = (t < NS) ? pmz[b * NS + t] : 0.f;
    float vw = (t < NS) ? pmw[b * NS + t] : 0.f;
#pragma unroll
    for (int o = 32; o; o >>= 1) {
        vz = fmaxf(vz, __shfl_xor(vz, o, 64));
        vw = fmaxf(vw, __shfl_xor(vw, o, 64));
    }
    if (t < N_CHEBY) {
        const float m = vw / vz;
        const double rr = cos(M_PI * (2.0 * t + 1.0) / (2.0 * N_CHEBY));
        const float denom = m + m / 3.0f - (m / 3.0f - m) * (float)rr;
        taus[t * BB + b] = 2.0f / denom;
    }
}

// ---------------------------------------------------------------------------
// Fused FDv-level Chebyshev pass (proven round-10 config FD=5 @ RR=16):
// x_j = x_{j-1} + tau_{j-1}*(f - A x_{j-1}); f in a (2FDv-1)-deep register
// ring (level j uses fh[2(j-1)]); separate conflict-free re/ro float rings.
// ---------------------------------------------------------------------------
template<int FDv, int RR>
__global__ __launch_bounds__(256, 4) void cheby_fusedN(
    const float* __restrict__ xin, const float* __restrict__ fin,
    const float* __restrict__ kern, const float* __restrict__ tauv,
    float* __restrict__ xout)
{
    const int b = blockIdx.y, stripe = blockIdx.x, ytop = stripe * RR;
    const int t = threadIdx.x, c2 = t << 1;

    __shared__ float re[FDv - 1][2][258], ro[FDv - 1][2][258];

    if (t < 2 * (FDv - 1)) {
        const int l = t >> 1, par = t & 1;
        re[l][par][0] = 0.f; re[l][par][257] = 0.f;
        ro[l][par][0] = 0.f; ro[l][par][257] = 0.f;
    }
    __syncthreads();

    const float* kb = kern + b * 9;
    const float k00=kb[0],k01=kb[1],k02=kb[2],k10=kb[3],k11=kb[4],k12=kb[5],
                k20=kb[6],k21=kb[7],k22=kb[8];
    float tau[FDv];
#pragma unroll
    for (int j = 0; j < FDv; ++j) tau[j] = tauv[j * BB + b];

    const float* xp = xin + (size_t)b * PLANE;
    const float* fp = fin + (size_t)b * PLANE;
    float* op = xout + (size_t)b * PLANE;

    Sl u2 = {0,0,0,0}, u1 = {0,0,0,0};
    Sl ltp[FDv - 1], lmd[FDv - 1];
    float own0[FDv - 1], own1[FDv - 1];
#pragma unroll
    for (int l = 0; l < FDv - 1; ++l) {
        ltp[l] = Sl{0,0,0,0}; lmd[l] = Sl{0,0,0,0};
        own0[l] = 0.f; own1[l] = 0.f;
    }
    float2 fh[2 * FDv - 1];
#pragma unroll
    for (int k = 1; k < 2 * FDv - 1; ++k) fh[k] = make_float2(0.f, 0.f);

    Sl u0 = ldsl(xp, ytop - FDv, c2, (unsigned)(ytop - FDv) < HH);
    {
        const int yf = ytop - FDv - 1;
        fh[0] = ((unsigned)yf < HH)
            ? *reinterpret_cast<const float2*>(fp + (size_t)yf * WW + c2)
            : make_float2(0.f, 0.f);
    }

    const int STEPS   = RR + 3 * FDv - 1;
    const int LOADCUT = RR + 2 * FDv - 1;
#pragma unroll 2
    for (int p = 0; p < STEPS; ++p) {
        const int yu = ytop - FDv + p;
        const bool ldok = (p < LOADCUT);
        Sl un = ldsl(xp, yu + 1, c2, ((unsigned)(yu + 1) < HH) && ldok);
        const float2 fn = (((unsigned)yu < HH) && ldok)
            ? *reinterpret_cast<const float2*>(fp + (size_t)yu * WW + c2)
            : make_float2(0.f, 0.f);

        const int rpar = (p + 1) & 1, wpar = p & 1;
        Sl am[FDv - 1];
#pragma unroll
        for (int l = 0; l < FDv - 1; ++l) {
            am[l].a = ro[l][rpar][t];
            am[l].b = own0[l];
            am[l].c = own1[l];
            am[l].d = re[l][rpar][2 + t];
        }

        float v0[FDv], v1[FDv];
        {   // level 1: x1 = x + tau0*(f - A x)   at row yu-1
            float s0 = 0.f, s1 = 0.f;
            racc(u2, k00,k01,k02, s0,s1);
            racc(u1, k10,k11,k12, s0,s1);
            racc(u0, k20,k21,k22, s0,s1);
            const int y = yu - 1;
            const bool act = (y >= ytop - (FDv-1)) && (y <= ytop + RR + FDv - 2)
                          && ((unsigned)y < HH);
            v0[0] = act ? fmaf(tau[0], fh[0].x - s0, u1.b) : 0.f;
            v1[0] = act ? fmaf(tau[0], fh[0].y - s1, u1.c) : 0.f;
        }
#pragma unroll
        for (int j = 2; j <= FDv; ++j) {
            float s0 = 0.f, s1 = 0.f;
            racc(ltp[j-2], k00,k01,k02, s0,s1);
            racc(lmd[j-2], k10,k11,k12, s0,s1);
            racc(am[j-2],  k20,k21,k22, s0,s1);
            const int y = yu - (2*j - 1);
            const float2 fv = fh[2*(j-1)];
            if (j < FDv) {
                const bool act = (y >= ytop - (FDv-j)) && (y <= ytop + RR + FDv - j - 1)
                              && ((unsigned)y < HH);
                v0[j-1] = act ? fmaf(tau[j-1], fv.x - s0, lmd[j-2].b) : 0.f;
                v1[j-1] = act ? fmaf(tau[j-1], fv.y - s1, lmd[j-2].c) : 0.f;
            } else {
                if (y >= ytop && y < ytop + RR) {
                    const float o0 = fmaf(tau[FDv-1], fv.x - s0, lmd[j-2].b);
                    const float o1 = fmaf(tau[FDv-1], fv.y - s1, lmd[j-2].c);
                    *reinterpret_cast<float2*>(op + (size_t)y * WW + c2) =
                        make_float2(o0, o1);
                }
            }
        }
#pragma unroll
        for (int l = 0; l < FDv - 1; ++l) {
            re[l][wpar][1 + t] = v0[l];
            ro[l][wpar][1 + t] = v1[l];
            ltp[l] = lmd[l]; lmd[l] = am[l];
            own0[l] = v0[l]; own1[l] = v1[l];
        }
        u2 = u1; u1 = u0; u0 = un;
#pragma unroll
        for (int k = 2 * FDv - 2; k > 0; --k) fh[k] = fh[k - 1];
        fh[0] = fn;
        softbar();
    }
}

extern "C" void kernel_launch(void* const* d_in, const int* in_sizes, int n_in,
                              void* d_out, int out_size, void* d_ws, size_t ws_size,
                              hipStream_t stream)
{
    const float* x_in = (const float*)d_in[0];
    const float* f_in = (const float*)d_in[1];
    const float* k_in = (const float*)d_in[2];
    const float* u_in = (const float*)d_in[3];
    float* out = (float*)d_out;

    float* bufA = (float*)d_ws;                 // 64 MB field
    float* pmW0 = bufA + (size_t)BB * PLANE;    // [BB*32] each
    float* pmW1 = pmW0 + BB * 32;
    float* pmZ  = pmW1 + BB * 32;
    float* taus = pmZ  + BB * 32;               // [15*BB]

    dim3 blk(256);

    // ---- 4 fused power passes, FD=5 @ R=16 (grid 2048, 4 blocks/CU) ----
    conv_fusedN<5, 16><<<dim3(32, BB), blk, 0, stream>>>(
        u_in, k_in, nullptr, bufA, pmW0, pmZ);
    conv_fusedN<5, 16><<<dim3(32, BB), blk, 0, stream>>>(
        bufA, k_in, pmW0, out, pmW1, pmZ);
    conv_fusedN<5, 16><<<dim3(32, BB), blk, 0, stream>>>(
        out, k_in, pmW1, bufA, pmW0, pmZ);
    conv_fusedN<5, 16><<<dim3(32, BB), blk, 0, stream>>>(
        bufA, k_in, pmW0, nullptr, pmW1, pmZ);

    tau_fused<<<BB, 64, 0, stream>>>(pmZ, pmW1, taus);

    // ---- 3 fused Chebyshev passes, FD=5 @ R=16 (proven round-10 config) ----
    cheby_fusedN<5, 16><<<dim3(32, BB), blk, 0, stream>>>(
        x_in, f_in, k_in, taus, out);
    cheby_fusedN<5, 16><<<dim3(32, BB), blk, 0, stream>>>(
        out,  f_in, k_in, taus + 5 * BB, bufA);
    cheby_fusedN<5, 16><<<dim3(32, BB), blk, 0, stream>>>(
        bufA, f_in, k_in, taus + 10 * BB, out);
}

// Round 14
// 383.702 us; speedup vs baseline: 1.1100x; 1.1100x over previous
//
#include <hip/hip_runtime.h>

#define BB 64
#define HH 512
#define WW 512
#define PLANE (HH * WW)
#define N_CHEBY 15
#define FD 5
#define RR 32
#define NS (HH / RR)          // 16 stripes
#define STEPS (RR + 2 * FD)   // 42  (divisible by 6 for the unroll)

struct F8 { float v[8]; };

// wave-wide lane shifts with zero fill at wave edge (= plane column padding)
__device__ __forceinline__ float wshr1(float x) {  // lane i <- lane i-1; lane0 <- 0
    return __int_as_float(__builtin_amdgcn_update_dpp(
        0, __float_as_int(x), 0x138, 0xF, 0xF, true));
}
__device__ __forceinline__ float wshl1(float x) {  // lane i <- lane i+1; lane63 <- 0
    return __int_as_float(__builtin_amdgcn_update_dpp(
        0, __float_as_int(x), 0x130, 0xF, 0xF, true));
}

// lane owns cols [8*lane, 8*lane+8)
__device__ __forceinline__ F8 ldrow(const float* plane, int y, int lane, bool ok) {
    F8 r;
    if (ok) {
        const float4* p =
            reinterpret_cast<const float4*>(plane + (size_t)y * WW + (lane << 3));
        const float4 a = p[0], b = p[1];
        r.v[0] = a.x; r.v[1] = a.y; r.v[2] = a.z; r.v[3] = a.w;
        r.v[4] = b.x; r.v[5] = b.y; r.v[6] = b.z; r.v[7] = b.w;
    } else {
#pragma unroll
        for (int i = 0; i < 8; ++i) r.v[i] = 0.f;
    }
    return r;
}

__device__ __forceinline__ void racc8(const F8& r, float k0, float k1, float k2,
                                      float acc[8]) {
    const float lf = wshr1(r.v[7]);   // col 8L-1
    const float rt = wshl1(r.v[0]);   // col 8L+8
    acc[0] = fmaf(k0, lf, fmaf(k1, r.v[0], fmaf(k2, r.v[1], acc[0])));
#pragma unroll
    for (int c = 1; c < 7; ++c)
        acc[c] = fmaf(k0, r.v[c-1], fmaf(k1, r.v[c], fmaf(k2, r.v[c+1], acc[c])));
    acc[7] = fmaf(k0, r.v[6], fmaf(k1, r.v[7], fmaf(k2, rt, acc[7])));
}

// ---------------------------------------------------------------------------
// Barrier-free fused power pass: each wave owns one RR-row stripe, full width.
// Levels chain with lag 1: level j at step p computes row yL-j, where yL is
// the row loaded this step. v1 = invv*A(in); v_{j+1} = A(v_j).
// mz = stripe max|v_{FD-1}|, mw = stripe max|v_FD|. out==null -> no store.
// ---------------------------------------------------------------------------
__global__ __launch_bounds__(256, 1) void conv_wave(
    const float* __restrict__ in, const float* __restrict__ kern,
    const float* __restrict__ pm_prev, float* __restrict__ out,
    float* __restrict__ pmw, float* __restrict__ pmz)
{
    const int lane = threadIdx.x & 63;
    const int wid  = threadIdx.x >> 6;
    const int b = blockIdx.y;
    const int stripe = (blockIdx.x << 2) + wid;
    const int ytop = stripe * RR;

    float invv = 1.f;
    if (pm_prev) {
        float v = (lane < NS) ? pm_prev[b * NS + lane] : 0.f;
#pragma unroll
        for (int o = 32; o; o >>= 1) v = fmaxf(v, __shfl_xor(v, o, 64));
        invv = 1.f / v;
    }

    const float* kb = kern + b * 9;
    const float k00=kb[0],k01=kb[1],k02=kb[2],k10=kb[3],k11=kb[4],k12=kb[5],
                k20=kb[6],k21=kb[7],k22=kb[8];
    const float* ip = in + (size_t)b * PLANE;
    float* op = out ? out + (size_t)b * PLANE : nullptr;

    F8 u2 = {}, u1 = {};
    F8 lt[FD - 1] = {}, lm[FD - 1] = {};
    float mz = 0.f, mw = 0.f;
    F8 u0 = ldrow(ip, ytop - FD, lane, (unsigned)(ytop - FD) < HH);

#pragma unroll 6
    for (int p = 0; p < STEPS; ++p) {
        const int yL = ytop - FD + p;
        F8 un = ldrow(ip, yL + 1, lane,
                      (p < STEPS - 1) && ((unsigned)(yL + 1) < HH));

        F8 nw[FD - 1];
        {   // level 1: row y = yL-1
            float acc[8] = {0,0,0,0,0,0,0,0};
            racc8(u2, k00,k01,k02, acc);
            racc8(u1, k10,k11,k12, acc);
            racc8(u0, k20,k21,k22, acc);
            const int y = yL - 1;
            const bool act = (y >= ytop - (FD-1)) && (y <= ytop + RR + FD - 2)
                          && ((unsigned)y < HH);
#pragma unroll
            for (int c = 0; c < 8; ++c) nw[0].v[c] = act ? acc[c] * invv : 0.f;
        }
#pragma unroll
        for (int j = 2; j <= FD; ++j) {
            float acc[8] = {0,0,0,0,0,0,0,0};
            racc8(lt[j-2], k00,k01,k02, acc);
            racc8(lm[j-2], k10,k11,k12, acc);
            racc8(nw[j-2], k20,k21,k22, acc);
            const int y = yL - j;
            if (j < FD) {
                const bool act = (y >= ytop - (FD-j)) && (y <= ytop + RR + FD - j - 1)
                              && ((unsigned)y < HH);
#pragma unroll
                for (int c = 0; c < 8; ++c) nw[j-1].v[c] = act ? acc[c] : 0.f;
                if (j == FD - 1) {
#pragma unroll
                    for (int c = 0; c < 8; ++c)
                        mz = fmaxf(mz, fabsf(nw[j-1].v[c]));
                }
            } else {
                if (y >= ytop && y < ytop + RR) {
#pragma unroll
                    for (int c = 0; c < 8; ++c) mw = fmaxf(mw, fabsf(acc[c]));
                    if (op) {
                        float4* q = reinterpret_cast<float4*>(
                            op + (size_t)y * WW + (lane << 3));
                        q[0] = make_float4(acc[0], acc[1], acc[2], acc[3]);
                        q[1] = make_float4(acc[4], acc[5], acc[6], acc[7]);
                    }
                }
            }
        }
#pragma unroll
        for (int l = 0; l < FD - 1; ++l) { lt[l] = lm[l]; lm[l] = nw[l]; }
        u2 = u1; u1 = u0; u0 = un;
    }

#pragma unroll
    for (int o = 32; o; o >>= 1) {
        mz = fmaxf(mz, __shfl_xor(mz, o, 64));
        mw = fmaxf(mw, __shfl_xor(mw, o, 64));
    }
    if (lane == 0) {
        pmz[b * NS + stripe] = mz;
        pmw[b * NS + stripe] = mw;
    }
}

// m = max|v20| / max|v19|; taus[it*BB + b]
__global__ __launch_bounds__(64) void tau_k(
    const float* __restrict__ pmz, const float* __restrict__ pmw,
    float* __restrict__ taus)
{
    const int b = blockIdx.x, t = threadIdx.x;
    float vz = (t < NS) ? pmz[b * NS + t] : 0.f;
    float vw = (t < NS) ? pmw[b * NS + t] : 0.f;
#pragma unroll
    for (int o = 32; o; o >>= 1) {
        vz = fmaxf(vz, __shfl_xor(vz, o, 64));
        vw = fmaxf(vw, __shfl_xor(vw, o, 64));
    }
    if (t < N_CHEBY) {
        const float m = vw / vz;
        const double rr = cos(M_PI * (2.0 * t + 1.0) / (2.0 * N_CHEBY));
        const float denom = m + m / 3.0f - (m / 3.0f - m) * (float)rr;
        taus[t * BB + b] = 2.0f / denom;
    }
}

// ---------------------------------------------------------------------------
// Barrier-free fused Chebyshev pass: x_j = x_{j-1} + tau_{j-1}*(f - A x_{j-1}),
// lag-1 levels; f carried in a per-wave, per-lane-private LDS ring (depth 6,
// no cross-lane access -> no barrier). Level j taps ring slot (p-j) mod 6.
// ---------------------------------------------------------------------------
__global__ __launch_bounds__(256, 1) void cheby_wave(
    const float* __restrict__ xin, const float* __restrict__ fin,
    const float* __restrict__ kern, const float* __restrict__ tauv,
    float* __restrict__ xout)
{
    __shared__ float fring[4][FD + 1][WW];   // 4 waves x 6 slots x 512 = 48 KB
    const int lane = threadIdx.x & 63;
    const int wid  = threadIdx.x >> 6;
    const int b = blockIdx.y;
    const int stripe = (blockIdx.x << 2) + wid;
    const int ytop = stripe * RR;
    float* fr = &fring[wid][0][0];

    const float* kb = kern + b * 9;
    const float k00=kb[0],k01=kb[1],k02=kb[2],k10=kb[3],k11=kb[4],k12=kb[5],
                k20=kb[6],k21=kb[7],k22=kb[8];
    float tau[FD];
#pragma unroll
    for (int j = 0; j < FD; ++j) tau[j] = tauv[j * BB + b];

    const float* xp = xin + (size_t)b * PLANE;
    const float* fp = fin + (size_t)b * PLANE;
    float* op = xout + (size_t)b * PLANE;

    F8 u2 = {}, u1 = {};
    F8 lt[FD - 1] = {}, lm[FD - 1] = {};
    F8 u0 = ldrow(xp, ytop - FD, lane, (unsigned)(ytop - FD) < HH);

#pragma unroll 6
    for (int p = 0; p < STEPS; ++p) {
        const int yL = ytop - FD + p;
        F8 un = ldrow(xp, yL + 1, lane,
                      (p < STEPS - 1) && ((unsigned)(yL + 1) < HH));
        F8 fn = ldrow(fp, yL, lane, (p < STEPS - 1) && ((unsigned)yL < HH));

        // f taps: level j uses f(yL-j) = ring slot (p-j) mod 6
        F8 ft[FD];
#pragma unroll
        for (int j = 1; j <= FD; ++j) {
            const int sp = (p + (FD + 1) - j) % (FD + 1);
            const float4* q =
                reinterpret_cast<const float4*>(&fr[sp * WW + (lane << 3)]);
            const float4 a = q[0], bb = q[1];
            ft[j-1].v[0] = a.x; ft[j-1].v[1] = a.y;
            ft[j-1].v[2] = a.z; ft[j-1].v[3] = a.w;
            ft[j-1].v[4] = bb.x; ft[j-1].v[5] = bb.y;
            ft[j-1].v[6] = bb.z; ft[j-1].v[7] = bb.w;
        }

        F8 nw[FD - 1];
        {   // level 1: row y = yL-1; x1 = x0 + tau0*(f - A x0)
            float acc[8] = {0,0,0,0,0,0,0,0};
            racc8(u2, k00,k01,k02, acc);
            racc8(u1, k10,k11,k12, acc);
            racc8(u0, k20,k21,k22, acc);
            const int y = yL - 1;
            const bool act = (y >= ytop - (FD-1)) && (y <= ytop + RR + FD - 2)
                          && ((unsigned)y < HH);
#pragma unroll
            for (int c = 0; c < 8; ++c)
                nw[0].v[c] = act ? fmaf(tau[0], ft[0].v[c] - acc[c], u1.v[c]) : 0.f;
        }
#pragma unroll
        for (int j = 2; j <= FD; ++j) {
            float acc[8] = {0,0,0,0,0,0,0,0};
            racc8(lt[j-2], k00,k01,k02, acc);
            racc8(lm[j-2], k10,k11,k12, acc);
            racc8(nw[j-2], k20,k21,k22, acc);
            const int y = yL - j;
            if (j < FD) {
                const bool act = (y >= ytop - (FD-j)) && (y <= ytop + RR + FD - j - 1)
                              && ((unsigned)y < HH);
#pragma unroll
                for (int c = 0; c < 8; ++c)
                    nw[j-1].v[c] =
                        act ? fmaf(tau[j-1], ft[j-1].v[c] - acc[c], lm[j-2].v[c])
                            : 0.f;
            } else {
                if (y >= ytop && y < ytop + RR) {
                    float4* q = reinterpret_cast<float4*>(
                        op + (size_t)y * WW + (lane << 3));
                    float o0 = fmaf(tau[FD-1], ft[FD-1].v[0] - acc[0], lm[j-2].v[0]);
                    float o1 = fmaf(tau[FD-1], ft[FD-1].v[1] - acc[1], lm[j-2].v[1]);
                    float o2 = fmaf(tau[FD-1], ft[FD-1].v[2] - acc[2], lm[j-2].v[2]);
                    float o3 = fmaf(tau[FD-1], ft[FD-1].v[3] - acc[3], lm[j-2].v[3]);
                    q[0] = make_float4(o0, o1, o2, o3);
                    o0 = fmaf(tau[FD-1], ft[FD-1].v[4] - acc[4], lm[j-2].v[4]);
                    o1 = fmaf(tau[FD-1], ft[FD-1].v[5] - acc[5], lm[j-2].v[5]);
                    o2 = fmaf(tau[FD-1], ft[FD-1].v[6] - acc[6], lm[j-2].v[6]);
                    o3 = fmaf(tau[FD-1], ft[FD-1].v[7] - acc[7], lm[j-2].v[7]);
                    q[1] = make_float4(o0, o1, o2, o3);
                }
            }
        }

        // write f(yL) into ring slot p mod 6 (never read within this step)
        if (p < STEPS - 1) {
            float4* q = reinterpret_cast<float4*>(
                &fr[(p % (FD + 1)) * WW + (lane << 3)]);
            q[0] = make_float4(fn.v[0], fn.v[1], fn.v[2], fn.v[3]);
            q[1] = make_float4(fn.v[4], fn.v[5], fn.v[6], fn.v[7]);
        }

#pragma unroll
        for (int l = 0; l < FD - 1; ++l) { lt[l] = lm[l]; lm[l] = nw[l]; }
        u2 = u1; u1 = u0; u0 = un;
    }
}

extern "C" void kernel_launch(void* const* d_in, const int* in_sizes, int n_in,
                              void* d_out, int out_size, void* d_ws, size_t ws_size,
                              hipStream_t stream)
{
    const float* x_in = (const float*)d_in[0];
    const float* f_in = (const float*)d_in[1];
    const float* k_in = (const float*)d_in[2];
    const float* u_in = (const float*)d_in[3];
    float* out = (float*)d_out;

    float* bufA = (float*)d_ws;                 // 64 MB field
    float* pmW0 = bufA + (size_t)BB * PLANE;    // [BB*NS] each
    float* pmW1 = pmW0 + BB * NS;
    float* pmZ  = pmW1 + BB * NS;
    float* taus = pmZ  + BB * NS;               // [15*BB]

    dim3 blk(256), grd(NS / 4, BB);             // 4 waves/block, 1 stripe/wave

    // ---- 4 fused power passes (5 levels each = 20 iterations) ----
    conv_wave<<<grd, blk, 0, stream>>>(u_in, k_in, nullptr, bufA, pmW0, pmZ);
    conv_wave<<<grd, blk, 0, stream>>>(bufA, k_in, pmW0, out,  pmW1, pmZ);
    conv_wave<<<grd, blk, 0, stream>>>(out,  k_in, pmW1, bufA, pmW0, pmZ);
    conv_wave<<<grd, blk, 0, stream>>>(bufA, k_in, pmW0, nullptr, pmW1, pmZ);

    tau_k<<<BB, 64, 0, stream>>>(pmZ, pmW1, taus);

    // ---- 3 fused Chebyshev passes (5 steps each = 15) ----
    cheby_wave<<<grd, blk, 0, stream>>>(x_in, f_in, k_in, taus,          out);
    cheby_wave<<<grd, blk, 0, stream>>>(out,  f_in, k_in, taus + 5 * BB, bufA);
    cheby_wave<<<grd, blk, 0, stream>>>(bufA, f_in, k_in, taus + 10 * BB, out);
}

// Round 15
// 343.249 us; speedup vs baseline: 1.2409x; 1.1179x over previous
//
#include <hip/hip_runtime.h>

#define BB 64
#define HH 512
#define WW 512
#define PLANE (HH * WW)
#define N_CHEBY 15
#define FD 5
#define RR 32
#define NS (HH / RR)          // 16 stripes (conv)
#define STEPS (RR + 2 * FD)   // 42

struct F8 { float v[8]; };

// wave-wide lane shifts with zero fill at wave edge (= plane column padding)
__device__ __forceinline__ float wshr1(float x) {  // lane i <- lane i-1; lane0 <- 0
    return __int_as_float(__builtin_amdgcn_update_dpp(
        0, __float_as_int(x), 0x138, 0xF, 0xF, true));
}
__device__ __forceinline__ float wshl1(float x) {  // lane i <- lane i+1; lane63 <- 0
    return __int_as_float(__builtin_amdgcn_update_dpp(
        0, __float_as_int(x), 0x130, 0xF, 0xF, true));
}

// lane owns cols [8*lane, 8*lane+8)
__device__ __forceinline__ F8 ldrow(const float* plane, int y, int lane, bool ok) {
    F8 r;
    if (ok) {
        const float4* p =
            reinterpret_cast<const float4*>(plane + (size_t)y * WW + (lane << 3));
        const float4 a = p[0], b = p[1];
        r.v[0] = a.x; r.v[1] = a.y; r.v[2] = a.z; r.v[3] = a.w;
        r.v[4] = b.x; r.v[5] = b.y; r.v[6] = b.z; r.v[7] = b.w;
    } else {
#pragma unroll
        for (int i = 0; i < 8; ++i) r.v[i] = 0.f;
    }
    return r;
}

__device__ __forceinline__ void racc8(const F8& r, float k0, float k1, float k2,
                                      float acc[8]) {
    const float lf = wshr1(r.v[7]);   // col 8L-1
    const float rt = wshl1(r.v[0]);   // col 8L+8
    acc[0] = fmaf(k0, lf, fmaf(k1, r.v[0], fmaf(k2, r.v[1], acc[0])));
#pragma unroll
    for (int c = 1; c < 7; ++c)
        acc[c] = fmaf(k0, r.v[c-1], fmaf(k1, r.v[c], fmaf(k2, r.v[c+1], acc[c])));
    acc[7] = fmaf(k0, r.v[6], fmaf(k1, r.v[7], fmaf(k2, rt, acc[7])));
}

// ---------------------------------------------------------------------------
// Barrier-free fused power pass (PROVEN round-14: ~27 us/pass): wave owns one
// RR=32 stripe, lag-1 level chain, DPP column halos, no LDS, no barriers.
// ---------------------------------------------------------------------------
__global__ __launch_bounds__(256, 1) void conv_wave(
    const float* __restrict__ in, const float* __restrict__ kern,
    const float* __restrict__ pm_prev, float* __restrict__ out,
    float* __restrict__ pmw, float* __restrict__ pmz)
{
    const int lane = threadIdx.x & 63;
    const int wid  = threadIdx.x >> 6;
    const int b = blockIdx.y;
    const int stripe = (blockIdx.x << 2) + wid;
    const int ytop = stripe * RR;

    float invv = 1.f;
    if (pm_prev) {
        float v = (lane < NS) ? pm_prev[b * NS + lane] : 0.f;
#pragma unroll
        for (int o = 32; o; o >>= 1) v = fmaxf(v, __shfl_xor(v, o, 64));
        invv = 1.f / v;
    }

    const float* kb = kern + b * 9;
    const float k00=kb[0],k01=kb[1],k02=kb[2],k10=kb[3],k11=kb[4],k12=kb[5],
                k20=kb[6],k21=kb[7],k22=kb[8];
    const float* ip = in + (size_t)b * PLANE;
    float* op = out ? out + (size_t)b * PLANE : nullptr;

    F8 u2 = {}, u1 = {};
    F8 lt[FD - 1] = {}, lm[FD - 1] = {};
    float mz = 0.f, mw = 0.f;
    F8 u0 = ldrow(ip, ytop - FD, lane, (unsigned)(ytop - FD) < HH);

#pragma unroll 6
    for (int p = 0; p < STEPS; ++p) {
        const int yL = ytop - FD + p;
        F8 un = ldrow(ip, yL + 1, lane,
                      (p < STEPS - 1) && ((unsigned)(yL + 1) < HH));

        F8 nw[FD - 1];
        {   // level 1: row y = yL-1
            float acc[8] = {0,0,0,0,0,0,0,0};
            racc8(u2, k00,k01,k02, acc);
            racc8(u1, k10,k11,k12, acc);
            racc8(u0, k20,k21,k22, acc);
            const int y = yL - 1;
            const bool act = (y >= ytop - (FD-1)) && (y <= ytop + RR + FD - 2)
                          && ((unsigned)y < HH);
#pragma unroll
            for (int c = 0; c < 8; ++c) nw[0].v[c] = act ? acc[c] * invv : 0.f;
        }
#pragma unroll
        for (int j = 2; j <= FD; ++j) {
            float acc[8] = {0,0,0,0,0,0,0,0};
            racc8(lt[j-2], k00,k01,k02, acc);
            racc8(lm[j-2], k10,k11,k12, acc);
            racc8(nw[j-2], k20,k21,k22, acc);
            const int y = yL - j;
            if (j < FD) {
                const bool act = (y >= ytop - (FD-j)) && (y <= ytop + RR + FD - j - 1)
                              && ((unsigned)y < HH);
#pragma unroll
                for (int c = 0; c < 8; ++c) nw[j-1].v[c] = act ? acc[c] : 0.f;
                if (j == FD - 1) {
#pragma unroll
                    for (int c = 0; c < 8; ++c)
                        mz = fmaxf(mz, fabsf(nw[j-1].v[c]));
                }
            } else {
                if (y >= ytop && y < ytop + RR) {
#pragma unroll
                    for (int c = 0; c < 8; ++c) mw = fmaxf(mw, fabsf(acc[c]));
                    if (op) {
                        float4* q = reinterpret_cast<float4*>(
                            op + (size_t)y * WW + (lane << 3));
                        q[0] = make_float4(acc[0], acc[1], acc[2], acc[3]);
                        q[1] = make_float4(acc[4], acc[5], acc[6], acc[7]);
                    }
                }
            }
        }
#pragma unroll
        for (int l = 0; l < FD - 1; ++l) { lt[l] = lm[l]; lm[l] = nw[l]; }
        u2 = u1; u1 = u0; u0 = un;
    }

#pragma unroll
    for (int o = 32; o; o >>= 1) {
        mz = fmaxf(mz, __shfl_xor(mz, o, 64));
        mw = fmaxf(mw, __shfl_xor(mw, o, 64));
    }
    if (lane == 0) {
        pmz[b * NS + stripe] = mz;
        pmw[b * NS + stripe] = mw;
    }
}

// m = max|v20| / max|v19|; taus[it*BB + b]
__global__ __launch_bounds__(64) void tau_k(
    const float* __restrict__ pmz, const float* __restrict__ pmw,
    float* __restrict__ taus)
{
    const int b = blockIdx.x, t = threadIdx.x;
    float vz = (t < NS) ? pmz[b * NS + t] : 0.f;
    float vw = (t < NS) ? pmw[b * NS + t] : 0.f;
#pragma unroll
    for (int o = 32; o; o >>= 1) {
        vz = fmaxf(vz, __shfl_xor(vz, o, 64));
        vw = fmaxf(vw, __shfl_xor(vw, o, 64));
    }
    if (t < N_CHEBY) {
        const float m = vw / vz;
        const double rr = cos(M_PI * (2.0 * t + 1.0) / (2.0 * N_CHEBY));
        const float denom = m + m / 3.0f - (m / 3.0f - m) * (float)rr;
        taus[t * BB + b] = 2.0f / denom;
    }
}

// ---------------------------------------------------------------------------
// Barrier-free fused Chebyshev pass, RRv=16 stripes (8 waves/CU) and a
// TRANSPOSED per-wave f-ring fr[slot][c][lane]: all ring ops are lane-
// contiguous ds_read/write_b32 -> bank = lane%32 -> 2-way aliasing = free.
// Level j at step p taps f(yL-j) = slot (p-j) mod 6 (written at step p-j);
// pre-write reads (p<j) feed only act=false rows -> garbage never used.
// ---------------------------------------------------------------------------
template<int RRv>
__global__ __launch_bounds__(256, 2) void cheby_wave2(
    const float* __restrict__ xin, const float* __restrict__ fin,
    const float* __restrict__ kern, const float* __restrict__ tauv,
    float* __restrict__ xout)
{
    constexpr int NSv = HH / RRv;
    constexpr int STEPSv = RRv + 2 * FD;
    __shared__ float fring[4][FD + 1][8][64];   // 48 KB: 4 waves x 6 slots
    const int lane = threadIdx.x & 63;
    const int wid  = threadIdx.x >> 6;
    const int b = blockIdx.y;
    const int stripe = (blockIdx.x << 2) + wid;
    const int ytop = stripe * RRv;
    float (*fr)[8][64] = fring[wid];

    const float* kb = kern + b * 9;
    const float k00=kb[0],k01=kb[1],k02=kb[2],k10=kb[3],k11=kb[4],k12=kb[5],
                k20=kb[6],k21=kb[7],k22=kb[8];
    float tau[FD];
#pragma unroll
    for (int j = 0; j < FD; ++j) tau[j] = tauv[j * BB + b];

    const float* xp = xin + (size_t)b * PLANE;
    const float* fp = fin + (size_t)b * PLANE;
    float* op = xout + (size_t)b * PLANE;

    F8 u2 = {}, u1 = {};
    F8 lt[FD - 1] = {}, lm[FD - 1] = {};
    F8 u0 = ldrow(xp, ytop - FD, lane, (unsigned)(ytop - FD) < HH);

#pragma unroll 2
    for (int p = 0; p < STEPSv; ++p) {
        const int yL = ytop - FD + p;
        F8 un = ldrow(xp, yL + 1, lane,
                      (p < STEPSv - 1) && ((unsigned)(yL + 1) < HH));
        F8 fn = ldrow(fp, yL, lane, (p < STEPSv - 1) && ((unsigned)yL < HH));

        // f taps: level j uses slot (p-j) mod 6; conflict-free scalar reads
        F8 ft[FD];
#pragma unroll
        for (int j = 1; j <= FD; ++j) {
            const int sp = (p + (FD + 1) - j) % (FD + 1);
#pragma unroll
            for (int c = 0; c < 8; ++c) ft[j-1].v[c] = fr[sp][c][lane];
        }

        F8 nw[FD - 1];
        {   // level 1: row y = yL-1; x1 = x0 + tau0*(f - A x0)
            float acc[8] = {0,0,0,0,0,0,0,0};
            racc8(u2, k00,k01,k02, acc);
            racc8(u1, k10,k11,k12, acc);
            racc8(u0, k20,k21,k22, acc);
            const int y = yL - 1;
            const bool act = (y >= ytop - (FD-1)) && (y <= ytop + RRv + FD - 2)
                          && ((unsigned)y < HH);
#pragma unroll
            for (int c = 0; c < 8; ++c)
                nw[0].v[c] = act ? fmaf(tau[0], ft[0].v[c] - acc[c], u1.v[c]) : 0.f;
        }
#pragma unroll
        for (int j = 2; j <= FD; ++j) {
            float acc[8] = {0,0,0,0,0,0,0,0};
            racc8(lt[j-2], k00,k01,k02, acc);
            racc8(lm[j-2], k10,k11,k12, acc);
            racc8(nw[j-2], k20,k21,k22, acc);
            const int y = yL - j;
            if (j < FD) {
                const bool act = (y >= ytop - (FD-j)) && (y <= ytop + RRv + FD - j - 1)
                              && ((unsigned)y < HH);
#pragma unroll
                for (int c = 0; c < 8; ++c)
                    nw[j-1].v[c] =
                        act ? fmaf(tau[j-1], ft[j-1].v[c] - acc[c], lm[j-2].v[c])
                            : 0.f;
            } else {
                if (y >= ytop && y < ytop + RRv) {
                    float4* q = reinterpret_cast<float4*>(
                        op + (size_t)y * WW + (lane << 3));
                    float o0 = fmaf(tau[FD-1], ft[FD-1].v[0] - acc[0], lm[j-2].v[0]);
                    float o1 = fmaf(tau[FD-1], ft[FD-1].v[1] - acc[1], lm[j-2].v[1]);
                    float o2 = fmaf(tau[FD-1], ft[FD-1].v[2] - acc[2], lm[j-2].v[2]);
                    float o3 = fmaf(tau[FD-1], ft[FD-1].v[3] - acc[3], lm[j-2].v[3]);
                    q[0] = make_float4(o0, o1, o2, o3);
                    o0 = fmaf(tau[FD-1], ft[FD-1].v[4] - acc[4], lm[j-2].v[4]);
                    o1 = fmaf(tau[FD-1], ft[FD-1].v[5] - acc[5], lm[j-2].v[5]);
                    o2 = fmaf(tau[FD-1], ft[FD-1].v[6] - acc[6], lm[j-2].v[6]);
                    o3 = fmaf(tau[FD-1], ft[FD-1].v[7] - acc[7], lm[j-2].v[7]);
                    q[1] = make_float4(o0, o1, o2, o3);
                }
            }
        }

        // write f(yL) into slot p mod 6 (first read at step p+1)
        if (p < STEPSv - 1) {
            const int sp = p % (FD + 1);
#pragma unroll
            for (int c = 0; c < 8; ++c) fr[sp][c][lane] = fn.v[c];
        }

#pragma unroll
        for (int l = 0; l < FD - 1; ++l) { lt[l] = lm[l]; lm[l] = nw[l]; }
        u2 = u1; u1 = u0; u0 = un;
    }
}

extern "C" void kernel_launch(void* const* d_in, const int* in_sizes, int n_in,
                              void* d_out, int out_size, void* d_ws, size_t ws_size,
                              hipStream_t stream)
{
    const float* x_in = (const float*)d_in[0];
    const float* f_in = (const float*)d_in[1];
    const float* k_in = (const float*)d_in[2];
    const float* u_in = (const float*)d_in[3];
    float* out = (float*)d_out;

    float* bufA = (float*)d_ws;                 // 64 MB field
    float* pmW0 = bufA + (size_t)BB * PLANE;    // [BB*NS] each
    float* pmW1 = pmW0 + BB * NS;
    float* pmZ  = pmW1 + BB * NS;
    float* taus = pmZ  + BB * NS;               // [15*BB]

    dim3 blk(256);
    dim3 grdc(NS / 4, BB);                      // conv: 256 blocks, 1 stripe/wave

    // ---- 4 fused power passes (5 levels each = 20 iterations) ----
    conv_wave<<<grdc, blk, 0, stream>>>(u_in, k_in, nullptr, bufA, pmW0, pmZ);
    conv_wave<<<grdc, blk, 0, stream>>>(bufA, k_in, pmW0, out,  pmW1, pmZ);
    conv_wave<<<grdc, blk, 0, stream>>>(out,  k_in, pmW1, bufA, pmW0, pmZ);
    conv_wave<<<grdc, blk, 0, stream>>>(bufA, k_in, pmW0, nullptr, pmW1, pmZ);

    tau_k<<<BB, 64, 0, stream>>>(pmZ, pmW1, taus);

    // ---- 3 fused Chebyshev passes, RR=16 (512 blocks, 8 waves/CU) ----
    dim3 grdy((HH / 16) / 4, BB);
    cheby_wave2<16><<<grdy, blk, 0, stream>>>(x_in, f_in, k_in, taus,          out);
    cheby_wave2<16><<<grdy, blk, 0, stream>>>(out,  f_in, k_in, taus + 5 * BB, bufA);
    cheby_wave2<16><<<grdy, blk, 0, stream>>>(bufA, f_in, k_in, taus + 10 * BB, out);
}